// Round 13
// baseline (415.542 us; speedup 1.0000x reference)
//
#include <hip/hip_runtime.h>
#include <math.h>

#define NN 50000
#define NE 800000
#define NB 196        // dst buckets of 256 nodes
#define SLOT 8192     // fixed edge capacity per bucket (mean 4081, max ~4400)
#define PBH 8192      // halfs per packed 64x64 W block: 2ks*2hl*4ct*64lane*8

typedef float v4f __attribute__((ext_vector_type(4)));
typedef float v2f __attribute__((ext_vector_type(2)));
typedef _Float16 v8h __attribute__((ext_vector_type(8)));
typedef unsigned v4u __attribute__((ext_vector_type(4)));

// ---------------- fp8 e4m3fn helpers: HW builtins w/ fallback ----------------
__device__ __forceinline__ unsigned char enc8(float v) {
#if __has_builtin(__builtin_amdgcn_cvt_pk_fp8_f32)
  return (unsigned char)(__builtin_amdgcn_cvt_pk_fp8_f32(v, v, 0, false) & 0xFF);
#else
  unsigned u = __float_as_uint(v);
  unsigned s = (u >> 24) & 0x80u;
  unsigned au = u & 0x7fffffffu;
  float a = __uint_as_float(au);
  if (au < 0x3C800000u) {
    int m = (int)(a * 512.0f + 0.5f);
    if (m >= 8) return (unsigned char)(s | 8u);
    return (unsigned char)(s | (unsigned)m);
  }
  unsigned r = au + 0x7FFFFu + ((au >> 20) & 1u);
  unsigned e = (r >> 23) - 120u;
  unsigned man = (r >> 20) & 7u;
  if (e > 15u) { e = 15u; man = 6u; }
  return (unsigned char)(s | (e << 3) | man);
#endif
}

#if __has_builtin(__builtin_amdgcn_cvt_pk_f32_fp8)
#define DEC8_HW 1
#else
__device__ __forceinline__ float dec8_1(unsigned b) {
  unsigned s = (b & 0x80u) << 24;
  unsigned em = b & 0x7fu;
  float v;
  if (em >= 8u) v = __uint_as_float((((em >> 3) + 120u) << 23) | ((em & 7u) << 20));
  else v = (float)em * 0.001953125f;
  return __uint_as_float(__float_as_uint(v) | s);
}
#endif

__device__ __forceinline__ void dec8x8(uint2 u, float* f) {
#ifdef DEC8_HW
  v2f p0 = __builtin_amdgcn_cvt_pk_f32_fp8((int)u.x, false);
  v2f p1 = __builtin_amdgcn_cvt_pk_f32_fp8((int)u.x, true);
  v2f p2 = __builtin_amdgcn_cvt_pk_f32_fp8((int)u.y, false);
  v2f p3 = __builtin_amdgcn_cvt_pk_f32_fp8((int)u.y, true);
  f[0] = p0.x; f[1] = p0.y; f[2] = p1.x; f[3] = p1.y;
  f[4] = p2.x; f[5] = p2.y; f[6] = p3.x; f[7] = p3.y;
#else
#pragma unroll
  for (int i = 0; i < 4; ++i) f[i] = dec8_1((u.x >> (8 * i)) & 0xFF);
#pragma unroll
  for (int i = 0; i < 4; ++i) f[4 + i] = dec8_1((u.y >> (8 * i)) & 0xFF);
#endif
}
__device__ __forceinline__ void dec8x16(uint4 u, float* f) {
  dec8x8(make_uint2(u.x, u.y), f);
  dec8x8(make_uint2(u.z, u.w), f + 8);
}

// ============ weight pre-pack + zero-init (block 15) ==========================
struct WPackArgs {
  const float* w[15];
  int gidx[15];
  const float* skip;
  _Float16* outp;
  int* gcur;     // [NB] zeroed by block 15
  float* sv;     // [256] zeroed by block 15
  int* done;     // [1]  zeroed by block 15
};

__global__ __launch_bounds__(256) void k_wpack(WPackArgs A) {
  __shared__ float sw[4096];
  int b = blockIdx.x, t = threadIdx.x;
  if (b == 15) {
    if (t < NB) A.gcur[t] = 0;
    A.sv[t] = 0.f;
    if (t == 0) *A.done = 0;
    return;
  }
  const float* w = A.w[b];
#pragma unroll
  for (int i = 0; i < 4; ++i)
    *(float4*)&sw[i * 1024 + t * 4] = *(const float4*)(w + i * 1024 + t * 4);
  float gs = 1.f;
  if (A.gidx[b] >= 0) gs = 1.f / (1.f + __expf(-A.skip[A.gidx[b]]));
  __syncthreads();
#pragma unroll
  for (int i = 0; i < 4; ++i) {
    int u = t * 4 + i;   // u = ks*512 + hl*256 + ct*64 + lane
    int lane = u & 63, ct = (u >> 6) & 3, hl = (u >> 8) & 1, ks = (u >> 9) & 1;
    v8h val;
#pragma unroll
    for (int j = 0; j < 8; ++j) {
      int k = ks * 32 + ((lane >> 4) & 3) * 8 + j;
      int n = ct * 16 + (lane & 15);
      float f = sw[k * 64 + n] * gs;
      _Float16 h = (_Float16)f;
      val[j] = hl ? (_Float16)(f - (float)h) : h;
    }
    *(v8h*)(A.outp + (size_t)b * PBH + (size_t)u * 8) = val;
  }
}

// ============ graph build: fixed-slot scatter (no hist/scan) ==================
__global__ __launch_bounds__(256) void k_bscatter2(const int* __restrict__ src,
                                                   const int* __restrict__ dst,
                                                   int* __restrict__ gcur,
                                                   unsigned* __restrict__ ebuf) {
  __shared__ int cnt[NB];
  __shared__ int base[NB];
  int t = threadIdx.x;
  for (int i = t; i < NB; i += 256) cnt[i] = 0;
  __syncthreads();
  int eb = blockIdx.x * 4096;
  unsigned pk[16];
  int bk[16], lp[16];
#pragma unroll
  for (int i = 0; i < 16; ++i) {
    int e = eb + i * 256 + t;
    if (e < NE) {
      int d = dst[e];
      int b = d >> 8;
      pk[i] = ((unsigned)src[e] << 8) | (unsigned)(d & 255);
      bk[i] = b;
      lp[i] = atomicAdd(&cnt[b], 1);
    }
  }
  __syncthreads();
  for (int i = t; i < NB; i += 256)
    base[i] = cnt[i] ? (i * SLOT + atomicAdd(&gcur[i], cnt[i])) : 0;
  __syncthreads();
#pragma unroll
  for (int i = 0; i < 16; ++i) {
    int e = eb + i * 256 + t;
    if (e < NE) {
      int p = base[bk[i]] + lp[i];
      if (p < (bk[i] + 1) * SLOT)
        __builtin_nontemporal_store(pk[i], &ebuf[p]);   // overflow guard
    }
  }
}

// per-bucket degree + scan + csr scatter; writes offs/ends (slotted csr)
__global__ __launch_bounds__(256) void k_bbuild2(const unsigned* __restrict__ ebuf,
                                                 const int* __restrict__ gcur,
                                                 int* __restrict__ offs,
                                                 int* __restrict__ ends,
                                                 float* __restrict__ invd,
                                                 int* __restrict__ csr) {
  __shared__ int dcnt[256];
  __shared__ int cur[256];
  int t = threadIdx.x;
  int b = blockIdx.x;
  int node0 = b << 8;
  int es = b * SLOT;
  int ee = es + min(gcur[b], SLOT);
  dcnt[t] = 0;
  __syncthreads();
  for (int e = es + t; e < ee; e += 256) atomicAdd(&dcnt[ebuf[e] & 255], 1);
  __syncthreads();
  int v = dcnt[t];
  cur[t] = v;
  __syncthreads();
  for (int o = 1; o < 256; o <<= 1) {
    int u = (t >= o) ? cur[t - o] : 0;
    __syncthreads();
    cur[t] += u;
    __syncthreads();
  }
  int excl = cur[t] - v;
  int node = node0 + t;
  if (node < NN) {
    offs[node] = es + excl;
    ends[node] = es + excl + v;
    invd[node] = 1.0f / fmaxf((float)v, 1.0f);
  }
  __syncthreads();
  cur[t] = es + excl;
  __syncthreads();
  for (int e = es + t; e < ee; e += 256) {
    unsigned pk = ebuf[e];
    int p = atomicAdd(&cur[pk & 255], 1);
    __builtin_nontemporal_store((int)(pk >> 8), &csr[p]);
  }
}

// =================== compute-stage shared structs =============================
struct CArgs {
  const float* nf; const _Float16* wpk;
  const float* preb1; const float* preb2;
  const int* offs; const int* ends; const int* csr; const float* invd;
  _Float16 *x;
  unsigned char *f8a;
  float* sv;
  int* done;
  const float *pw1, *pb1, *pw2, *pb2, *pw3, *pb3, *pw4, *pb4;
  float* outp;
  int n;
};

struct FLinArgs {
  CArgs C;
  const _Float16* a[6];
  int pb[6];
  const unsigned char* gtab;
  const float* bias;
  _Float16* outp;
  unsigned char* out8;
  _Float16* mout;
  float* colsum;
};

// post-MLP; sv read via device-scope atomics (cross-XCD safe in last block)
__device__ __forceinline__ void post_body(int tt, const CArgs& A, float* Lf) {
  float* sh = Lf; float* h1 = Lf + 256; float* h2 = Lf + 320; float* h3 = Lf + 384;
  if (tt < 256) sh[tt] = atomicAdd(&A.sv[tt], 0.0f);
  __syncthreads();
  if (tt < 64) {
    float a = A.pb1[tt];
    for (int k = 0; k < 256; ++k) a += sh[k] * A.pw1[k * 64 + tt];
    h1[tt] = (a >= 0.f) ? a : 0.1f * a;
  }
  __syncthreads();
  if (tt < 64) {
    float a = A.pb2[tt];
    for (int k = 0; k < 64; ++k) a += h1[k] * A.pw2[k * 64 + tt];
    h2[tt] = fmaxf(a, 0.f);
  }
  __syncthreads();
  if (tt < 256) {
    float a = A.pb3[tt];
    for (int k = 0; k < 64; ++k) a += h2[k] * A.pw3[k * 256 + tt];
    h3[tt] = fmaxf(a, 0.f);
  }
  __syncthreads();
  if (tt < 64) {
    float a = A.pb4[tt];
    for (int k = 0; k < 256; ++k) a += h3[k] * A.pw4[k * 64 + tt];
    A.outp[tt] = a;
  }
}

// ====== fused gather+linear, 512 thr, K-split; NT stores keep L2 for gtab =====
template <int NSRC, int FUSED, int DOPOST>
__global__ __launch_bounds__(512) void k_lin(FLinArgs F) {
  __shared__ _Float16 atile[64 * 72];   // 9216B; epilogue scratch after barrier
  __shared__ float cbuf[64 * 65];       // K-split combine, padded
  __shared__ int lastflag;
  const CArgs& C = F.C;
  const int t    = threadIdx.x;
  const int lane = t & 63;
  const int w    = t >> 6;      // 0..7
  const int wq   = w & 3;       // row quadrant
  const int sg   = w >> 2;      // K-split group
  const int qd   = lane >> 4;
  const int ln   = lane & 15;
  const int n0   = blockIdx.x * 64;

  // ---------------- Phase A: gather (t = nd*8 + sl*4 + q) ----------------
  {
    const int nd = t >> 3;
    const int sl = (t >> 2) & 1;
    const int q  = t & 3;
    const int node = n0 + nd;
    float a[16];
#pragma unroll
    for (int i = 0; i < 16; ++i) a[i] = 0.f;
    float dinv = 0.f;
    if (node < C.n) {
      int s = C.offs[node], e = C.ends[node];
      dinv = C.invd[node];
      const unsigned char* fb = F.gtab;
      if (e > s) {
        int emax = e - 1;
        for (int p0 = s; p0 < e; p0 += 8) {
          int pa = p0 + sl, pb_ = p0 + 2 + sl, pc = p0 + 4 + sl, pd = p0 + 6 + sl;
          int ja = __builtin_nontemporal_load(C.csr + (pa < emax ? pa : emax));
          int jb = __builtin_nontemporal_load(C.csr + (pb_ < emax ? pb_ : emax));
          int jc = __builtin_nontemporal_load(C.csr + (pc < emax ? pc : emax));
          int jd = __builtin_nontemporal_load(C.csr + (pd < emax ? pd : emax));
          uint4 ua = *(const uint4*)(fb + (size_t)ja * 64 + q * 16);   // cached: reuse
          uint4 ub = *(const uint4*)(fb + (size_t)jb * 64 + q * 16);
          uint4 uc = *(const uint4*)(fb + (size_t)jc * 64 + q * 16);
          uint4 ud = *(const uint4*)(fb + (size_t)jd * 64 + q * 16);
          float f[16];
          dec8x16(ua, f);
          if (pa < e) {
#pragma unroll
            for (int i = 0; i < 16; ++i) a[i] += f[i];
          }
          dec8x16(ub, f);
          if (pb_ < e) {
#pragma unroll
            for (int i = 0; i < 16; ++i) a[i] += f[i];
          }
          dec8x16(uc, f);
          if (pc < e) {
#pragma unroll
            for (int i = 0; i < 16; ++i) a[i] += f[i];
          }
          dec8x16(ud, f);
          if (pd < e) {
#pragma unroll
            for (int i = 0; i < 16; ++i) a[i] += f[i];
          }
        }
      }
    }
#pragma unroll
    for (int i = 0; i < 16; ++i) a[i] += __shfl_xor(a[i], 4, 64);  // fold slots
    if (sl == 0) {
      v8h o0, o1;
#pragma unroll
      for (int i = 0; i < 8; ++i) {
        o0[i] = (_Float16)(a[i] * dinv);
        o1[i] = (_Float16)(a[8 + i] * dinv);
      }
      *(v8h*)(&atile[nd * 72 + q * 16]) = o0;
      *(v8h*)(&atile[nd * 72 + q * 16 + 8]) = o1;
      if (F.mout && node < C.n) {
        __builtin_nontemporal_store(o0, (v8h*)(F.mout + (size_t)node * 64 + q * 16));
        __builtin_nontemporal_store(o1, (v8h*)(F.mout + (size_t)node * 64 + q * 16 + 8));
      }
    }
  }
  __syncthreads();

  // ---------------- Phase B: MFMA, sources split across wave groups -----------
  v4f acc[4];
#pragma unroll
  for (int ct = 0; ct < 4; ++ct) acc[ct] = (v4f){0.f, 0.f, 0.f, 0.f};

  const int arow = n0 + wq * 16 + ln;
  const bool arv = arow < C.n;
  const int h = (NSRC + 1) >> 1;
  const int sbeg = sg ? h : 0;
  const int send = sg ? NSRC : h;
  v8h ah[2];

  for (int s = sbeg; s < send; ++s) {
    if (s == FUSED) {
      const _Float16* ph = atile + (wq * 16 + ln) * 72;
      ah[0] = *(const v8h*)(ph + qd * 8);
      ah[1] = *(const v8h*)(ph + 32 + qd * 8);
    } else if (arv) {
      const _Float16* ph = F.a[s] + (size_t)arow * 64;
      ah[0] = __builtin_nontemporal_load((const v8h*)(ph + qd * 8));      // read-once
      ah[1] = __builtin_nontemporal_load((const v8h*)(ph + 32 + qd * 8));
    } else {
      v8h z;
#pragma unroll
      for (int j = 0; j < 8; ++j) z[j] = (_Float16)0.f;
      ah[0] = ah[1] = z;
    }
    const _Float16* pw = C.wpk + (size_t)F.pb[s] * PBH;   // cached: reused by all
#pragma unroll
    for (int ks = 0; ks < 2; ++ks) {
#pragma unroll
      for (int ct = 0; ct < 4; ++ct) {
        const _Float16* pf = pw + (size_t)(ks * 512 + ct * 64 + lane) * 8;
        v8h bh = *(const v8h*)(pf);
        v8h bl = *(const v8h*)(pf + 2048);
        acc[ct] = __builtin_amdgcn_mfma_f32_16x16x32_f16(ah[ks], bh, acc[ct], 0, 0, 0);
        acc[ct] = __builtin_amdgcn_mfma_f32_16x16x32_f16(ah[ks], bl, acc[ct], 0, 0, 0);
      }
    }
  }

  // K-split combine: sg1 deposits, sg0 adds
  if (sg == 1) {
#pragma unroll
    for (int ct = 0; ct < 4; ++ct)
#pragma unroll
      for (int r = 0; r < 4; ++r) {
        int nb = wq * 16 + qd * 4 + r;
        cbuf[nb * 65 + ct * 16 + ln] = acc[ct][r];
      }
  }
  __syncthreads();

  unsigned char* f8t = (unsigned char*)atile;       // 4KB
  float* red = (float*)&atile[2304];                 // 1KB at byte 4608

  if (sg == 0) {
    float bvals[4];
#pragma unroll
    for (int ct = 0; ct < 4; ++ct) bvals[ct] = F.bias[ct * 16 + ln];
    float cs[4] = {0.f, 0.f, 0.f, 0.f};
#pragma unroll
    for (int ct = 0; ct < 4; ++ct) {
#pragma unroll
      for (int r = 0; r < 4; ++r) {
        int nb = wq * 16 + qd * 4 + r;   // C/D: row=(lane>>4)*4+reg, col=lane&15
        int node = n0 + nb;
        float v = acc[ct][r] + cbuf[nb * 65 + ct * 16 + ln] + bvals[ct];
        v = fmaxf(v, 0.f);   // relu (all lin stages)
        if (node < C.n) {
          if (F.outp)
            __builtin_nontemporal_store((_Float16)v,
                F.outp + (size_t)node * 64 + ct * 16 + ln);
          if (F.out8) f8t[nb * 64 + ct * 16 + ln] = enc8(v);
          cs[ct] += v;
        }
      }
    }
#pragma unroll
    for (int ct = 0; ct < 4; ++ct) {
      float v = cs[ct];
      v += __shfl_xor(v, 16, 64);
      v += __shfl_xor(v, 32, 64);
      if (qd == 0) red[wq * 64 + ct * 16 + ln] = v;
    }
  }
  __syncthreads();
  if (F.out8 && t < 256) {
    int row = t >> 2, ch = t & 3;
    if (n0 + row < C.n) {
      v4u val = *(const v4u*)(f8t + row * 64 + ch * 16);
      __builtin_nontemporal_store(val,
          (v4u*)(F.out8 + (size_t)(n0 + row) * 64 + ch * 16));
    }
  }
  if (t < 64) {
    float ssum = red[t] + red[64 + t] + red[128 + t] + red[192 + t];
    atomicAdd(&F.colsum[t], ssum);
  }

  if (DOPOST) {
    __syncthreads();
    __threadfence();
    if (t == 0)
      lastflag = (atomicAdd(C.done, 1) == (int)gridDim.x - 1);
    __syncthreads();
    if (lastflag) post_body(t, C, (float*)atile);
  }
}

// ============== fused pre-MLP (verified body); 256 thr; NT outputs ============
__global__ __launch_bounds__(256) void k_preF(CArgs A) {
  __shared__ _Float16 atile[64 * 72];
  const int t    = threadIdx.x;
  const int lane = t & 63;
  const int wv   = t >> 6;
  const int qd   = lane >> 4;
  const int ln   = lane & 15;
  const int n0   = blockIdx.x * 64;
  const int arow = n0 + wv * 16 + ln;
  const bool arv = arow < A.n;

  v4f acc[4];
#pragma unroll
  for (int ct = 0; ct < 4; ++ct) acc[ct] = (v4f){0.f, 0.f, 0.f, 0.f};
  v8h ah[2];

  auto domfma = [&](int pbi) {
    const _Float16* pw = A.wpk + (size_t)pbi * PBH;
#pragma unroll
    for (int ks = 0; ks < 2; ++ks) {
#pragma unroll
      for (int ct = 0; ct < 4; ++ct) {
        const _Float16* pf = pw + (size_t)(ks * 512 + ct * 64 + lane) * 8;
        v8h bh = *(const v8h*)(pf);
        v8h bl = *(const v8h*)(pf + 2048);
        acc[ct] = __builtin_amdgcn_mfma_f32_16x16x32_f16(ah[ks], bh, acc[ct], 0, 0, 0);
        acc[ct] = __builtin_amdgcn_mfma_f32_16x16x32_f16(ah[ks], bl, acc[ct], 0, 0, 0);
      }
    }
  };

  // stage 1: t0 = relu(nf@W1 + b1); K=128 as two 64-col sources (pb 0,1)
  for (int s = 0; s < 2; ++s) {
#pragma unroll
    for (int ks = 0; ks < 2; ++ks) {
      v8h hv;
      if (arv) {
        const float* p = A.nf + (size_t)arow * 128 + s * 64 + ks * 32 + qd * 8;
        float4 u0 = *(const float4*)(p);
        float4 u1 = *(const float4*)(p + 4);
        hv[0] = (_Float16)u0.x; hv[1] = (_Float16)u0.y;
        hv[2] = (_Float16)u0.z; hv[3] = (_Float16)u0.w;
        hv[4] = (_Float16)u1.x; hv[5] = (_Float16)u1.y;
        hv[6] = (_Float16)u1.z; hv[7] = (_Float16)u1.w;
      } else {
#pragma unroll
        for (int j = 0; j < 8; ++j) hv[j] = (_Float16)0.f;
      }
      ah[ks] = hv;
    }
    domfma(s);
  }

  float b1v[4];
#pragma unroll
  for (int ct = 0; ct < 4; ++ct) b1v[ct] = A.preb1[ct * 16 + ln];
#pragma unroll
  for (int ct = 0; ct < 4; ++ct) {
#pragma unroll
    for (int r = 0; r < 4; ++r) {
      int nb = wv * 16 + qd * 4 + r;
      float v = fmaxf(acc[ct][r] + b1v[ct], 0.f);
      atile[nb * 72 + ct * 16 + ln] = (_Float16)v;
    }
  }
#pragma unroll
  for (int ct = 0; ct < 4; ++ct) acc[ct] = (v4f){0.f, 0.f, 0.f, 0.f};
  __syncthreads();

  // stage 2: x = t0 @ W2 + b2 (pb 2)
  {
    const _Float16* ph = atile + (wv * 16 + ln) * 72;
    ah[0] = *(const v8h*)(ph + qd * 8);
    ah[1] = *(const v8h*)(ph + 32 + qd * 8);
  }
  domfma(2);

  float b2v[4];
#pragma unroll
  for (int ct = 0; ct < 4; ++ct) b2v[ct] = A.preb2[ct * 16 + ln];

  __syncthreads();   // all atile fragment reads complete; reuse as scratch
  unsigned char* f8t = (unsigned char*)atile;
  float* red = (float*)&atile[2304];
  float cs[4] = {0.f, 0.f, 0.f, 0.f};
#pragma unroll
  for (int ct = 0; ct < 4; ++ct) {
#pragma unroll
    for (int r = 0; r < 4; ++r) {
      int nb = wv * 16 + qd * 4 + r;
      int node = n0 + nb;
      float v = acc[ct][r] + b2v[ct];
      if (node < A.n) {
        __builtin_nontemporal_store((_Float16)v,
            A.x + (size_t)node * 64 + ct * 16 + ln);
        f8t[nb * 64 + ct * 16 + ln] = enc8(v);
        cs[ct] += v;
      }
    }
  }
#pragma unroll
  for (int ct = 0; ct < 4; ++ct) {
    float v = cs[ct];
    v += __shfl_xor(v, 16, 64);
    v += __shfl_xor(v, 32, 64);
    if (qd == 0) red[wv * 64 + ct * 16 + ln] = v;
  }
  __syncthreads();
  {
    int row = t >> 2, ch = t & 3;
    if (n0 + row < A.n) {
      v4u val = *(const v4u*)(f8t + row * 64 + ch * 16);
      __builtin_nontemporal_store(val,
          (v4u*)(A.f8a + (size_t)(n0 + row) * 64 + ch * 16));
    }
  }
  if (t < 64) {
    float ssum = red[t] + red[64 + t] + red[128 + t] + red[192 + t];
    atomicAdd(&A.sv[t], ssum);
  }
}

// ================================ launcher ====================================
extern "C" void kernel_launch(void* const* d_in, const int* in_sizes, int n_in,
                              void* d_out, int out_size, void* d_ws, size_t ws_size,
                              hipStream_t stream) {
  const float* nf     = (const float*)d_in[0];
  const int*   ei     = (const int*)d_in[1];
  const float* pre_w1 = (const float*)d_in[2];
  const float* pre_b1 = (const float*)d_in[3];
  const float* pre_w2 = (const float*)d_in[4];
  const float* pre_b2 = (const float*)d_in[5];
  const float* skip   = (const float*)d_in[6];
  const float* wl0 = (const float*)d_in[7],  *bl0 = (const float*)d_in[8],  *wr0 = (const float*)d_in[9];
  const float* wl1 = (const float*)d_in[10], *bl1 = (const float*)d_in[11], *wr1 = (const float*)d_in[12];
  const float* wl2 = (const float*)d_in[13], *bl2 = (const float*)d_in[14], *wr2 = (const float*)d_in[15];
  const float* pw1 = (const float*)d_in[16], *pb1 = (const float*)d_in[17];
  const float* pw2 = (const float*)d_in[18], *pb2 = (const float*)d_in[19];
  const float* pw3 = (const float*)d_in[20], *pb3 = (const float*)d_in[21];
  const float* pw4 = (const float*)d_in[22], *pb4 = (const float*)d_in[23];
  float* out = (float*)d_out;

  const int N = NN, E = NE;

  char* ws = (char*)d_ws;
  size_t pos = 0;
  auto alloc = [&](size_t bytes) {
    char* p = ws + pos;
    pos += (bytes + 255) & ~(size_t)255;
    return (void*)p;
  };
  int*      gcur  = (int*)alloc((size_t)NB * 4);
  unsigned* ebuf  = (unsigned*)alloc((size_t)NB * SLOT * 4);
  int*      offs  = (int*)alloc((size_t)N * 4);
  int*      ends  = (int*)alloc((size_t)N * 4);
  float*    invd  = (float*)alloc((size_t)N * 4);
  int*      csr   = (int*)alloc((size_t)NB * SLOT * 4);
  const size_t PB = (size_t)N * 64 * 2;
  _Float16* x  = (_Float16*)alloc(PB);
  _Float16* h0 = (_Float16*)alloc(PB);
  _Float16* h1 = (_Float16*)alloc(PB);
  _Float16* m0 = (_Float16*)alloc(PB);
  _Float16* m1 = (_Float16*)alloc(PB);
  unsigned char* f8a = (unsigned char*)alloc((size_t)N * 64);
  unsigned char* f8b = (unsigned char*)alloc((size_t)N * 64);
  _Float16* wpk = (_Float16*)alloc((size_t)15 * PBH * 2);
  float* sv = (float*)alloc(256 * 4);
  int* done = (int*)alloc(256);

  const int* e_src = ei;
  const int* e_dst = ei + E;
  const float* wsrc[15] = {pre_w1, pre_w1 + 64 * 64, pre_w2,
                           wl0, wr0,
                           wl1, wl1 + 64 * 64, wr1, wr1 + 64 * 64,
                           wl2, wl2 + 64 * 64, wl2 + 128 * 64,
                           wr2, wr2 + 64 * 64, wr2 + 128 * 64};
  const int gi[15] = {-1, -1, -1, 0, 0, 3, 4, 3, 4, 6, 7, 8, 6, 7, 8};

  // 1) weight pre-pack + zero-init (block 15)
  {
    WPackArgs W;
    for (int i = 0; i < 15; ++i) { W.w[i] = wsrc[i]; W.gidx[i] = gi[i]; }
    W.skip = skip; W.outp = wpk;
    W.gcur = gcur; W.sv = sv; W.done = done;
    k_wpack<<<16, 256, 0, stream>>>(W);
  }

  // 2) fixed-slot edge scatter, 3) per-bucket csr build
  const int EGRID = (E + 4095) / 4096;   // 196
  k_bscatter2<<<EGRID, 256, 0, stream>>>(e_src, e_dst, gcur, ebuf);
  k_bbuild2<<<NB, 256, 0, stream>>>(ebuf, gcur, offs, ends, invd, csr);

  CArgs C;
  C.nf = nf; C.wpk = wpk; C.preb1 = pre_b1; C.preb2 = pre_b2;
  C.offs = offs; C.ends = ends; C.csr = csr; C.invd = invd;
  C.x = x; C.f8a = f8a; C.sv = sv; C.done = done;
  C.pw1 = pw1; C.pb1 = pb1; C.pw2 = pw2; C.pb2 = pb2;
  C.pw3 = pw3; C.pb3 = pb3; C.pw4 = pw4; C.pb4 = pb4;
  C.outp = out; C.n = N;

  const int LGRID = (N + 63) / 64;   // 782

  // 4) fused pre-MLP: x (fp16) + f8a + colsum sv[0:64]
  k_preF<<<LGRID, 256, 0, stream>>>(C);

  // 5) layer 0: gather f8a -> m0; h0 = relu(m0@wl0 + x@wr0 + bl0); writes f8b
  {
    FLinArgs F; F.C = C;
    F.a[0] = nullptr; F.a[1] = x; F.a[2] = nullptr; F.a[3] = nullptr;
    F.a[4] = nullptr; F.a[5] = nullptr;
    F.pb[0] = 3; F.pb[1] = 4; F.pb[2] = 0; F.pb[3] = 0; F.pb[4] = 0; F.pb[5] = 0;
    F.gtab = f8a; F.bias = bl0;
    F.outp = h0; F.out8 = f8b; F.mout = m0; F.colsum = sv + 64;
    k_lin<2, 0, 0><<<LGRID, 512, 0, stream>>>(F);
  }

  // 6) layer 1: gather f8b -> m1; sources m0,(m1),x,h0; writes f8a
  {
    FLinArgs F; F.C = C;
    F.a[0] = m0; F.a[1] = nullptr; F.a[2] = x; F.a[3] = h0;
    F.a[4] = nullptr; F.a[5] = nullptr;
    F.pb[0] = 5; F.pb[1] = 6; F.pb[2] = 7; F.pb[3] = 8; F.pb[4] = 0; F.pb[5] = 0;
    F.gtab = f8b; F.bias = bl1;
    F.outp = h1; F.out8 = f8a; F.mout = m1; F.colsum = sv + 128;
    k_lin<4, 1, 0><<<LGRID, 512, 0, stream>>>(F);
  }

  // 7) layer 2: gather f8a -> (m2); colsum only; last block runs post-MLP
  {
    FLinArgs F; F.C = C;
    F.a[0] = m0; F.a[1] = m1; F.a[2] = nullptr; F.a[3] = x;
    F.a[4] = h0; F.a[5] = h1;
    F.pb[0] = 9; F.pb[1] = 10; F.pb[2] = 11; F.pb[3] = 12; F.pb[4] = 13; F.pb[5] = 14;
    F.gtab = f8a; F.bias = bl2;
    F.outp = nullptr; F.out8 = nullptr; F.mout = nullptr; F.colsum = sv + 192;
    k_lin<6, 2, 1><<<LGRID, 512, 0, stream>>>(F);
  }
}

// Round 14
// 350.600 us; speedup vs baseline: 1.1852x; 1.1852x over previous
//
#include <hip/hip_runtime.h>
#include <math.h>

#define NN 50000
#define NE 800000
#define NB 196        // dst buckets of 256 nodes
#define SLOT 8192     // fixed edge capacity per bucket (mean 4081, max ~4400)
#define PBH 8192      // halfs per packed 64x64 W block: 2ks*2hl*4ct*64lane*8
#define CH  768       // staged edges per chunk (48KB LDS rows)

typedef float v4f __attribute__((ext_vector_type(4)));
typedef float v2f __attribute__((ext_vector_type(2)));
typedef _Float16 v8h __attribute__((ext_vector_type(8)));

// ---------------- fp8 e4m3fn helpers: HW builtins w/ fallback ----------------
__device__ __forceinline__ unsigned char enc8(float v) {
#if __has_builtin(__builtin_amdgcn_cvt_pk_fp8_f32)
  return (unsigned char)(__builtin_amdgcn_cvt_pk_fp8_f32(v, v, 0, false) & 0xFF);
#else
  unsigned u = __float_as_uint(v);
  unsigned s = (u >> 24) & 0x80u;
  unsigned au = u & 0x7fffffffu;
  float a = __uint_as_float(au);
  if (au < 0x3C800000u) {
    int m = (int)(a * 512.0f + 0.5f);
    if (m >= 8) return (unsigned char)(s | 8u);
    return (unsigned char)(s | (unsigned)m);
  }
  unsigned r = au + 0x7FFFFu + ((au >> 20) & 1u);
  unsigned e = (r >> 23) - 120u;
  unsigned man = (r >> 20) & 7u;
  if (e > 15u) { e = 15u; man = 6u; }
  return (unsigned char)(s | (e << 3) | man);
#endif
}

#if __has_builtin(__builtin_amdgcn_cvt_pk_f32_fp8)
#define DEC8_HW 1
#else
__device__ __forceinline__ float dec8_1(unsigned b) {
  unsigned s = (b & 0x80u) << 24;
  unsigned em = b & 0x7fu;
  float v;
  if (em >= 8u) v = __uint_as_float((((em >> 3) + 120u) << 23) | ((em & 7u) << 20));
  else v = (float)em * 0.001953125f;
  return __uint_as_float(__float_as_uint(v) | s);
}
#endif

__device__ __forceinline__ void dec8x8(uint2 u, float* f) {
#ifdef DEC8_HW
  v2f p0 = __builtin_amdgcn_cvt_pk_f32_fp8((int)u.x, false);
  v2f p1 = __builtin_amdgcn_cvt_pk_f32_fp8((int)u.x, true);
  v2f p2 = __builtin_amdgcn_cvt_pk_f32_fp8((int)u.y, false);
  v2f p3 = __builtin_amdgcn_cvt_pk_f32_fp8((int)u.y, true);
  f[0] = p0.x; f[1] = p0.y; f[2] = p1.x; f[3] = p1.y;
  f[4] = p2.x; f[5] = p2.y; f[6] = p3.x; f[7] = p3.y;
#else
#pragma unroll
  for (int i = 0; i < 4; ++i) f[i] = dec8_1((u.x >> (8 * i)) & 0xFF);
#pragma unroll
  for (int i = 0; i < 4; ++i) f[4 + i] = dec8_1((u.y >> (8 * i)) & 0xFF);
#endif
}
__device__ __forceinline__ void dec8x16(uint4 u, float* f) {
  dec8x8(make_uint2(u.x, u.y), f);
  dec8x8(make_uint2(u.z, u.w), f + 8);
}

// ============ weight pre-pack + zero-init (block 15) ==========================
struct WPackArgs {
  const float* w[15];
  int gidx[15];
  const float* skip;
  _Float16* outp;
  int* gcur;     // [NB] zeroed by block 15
  float* sv;     // [256] zeroed by block 15
  int* done;     // [1]  zeroed by block 15
};

__global__ __launch_bounds__(256) void k_wpack(WPackArgs A) {
  __shared__ float sw[4096];
  int b = blockIdx.x, t = threadIdx.x;
  if (b == 15) {
    if (t < NB) A.gcur[t] = 0;
    A.sv[t] = 0.f;
    if (t == 0) *A.done = 0;
    return;
  }
  const float* w = A.w[b];
#pragma unroll
  for (int i = 0; i < 4; ++i)
    *(float4*)&sw[i * 1024 + t * 4] = *(const float4*)(w + i * 1024 + t * 4);
  float gs = 1.f;
  if (A.gidx[b] >= 0) gs = 1.f / (1.f + __expf(-A.skip[A.gidx[b]]));
  __syncthreads();
#pragma unroll
  for (int i = 0; i < 4; ++i) {
    int u = t * 4 + i;   // u = ks*512 + hl*256 + ct*64 + lane
    int lane = u & 63, ct = (u >> 6) & 3, hl = (u >> 8) & 1, ks = (u >> 9) & 1;
    v8h val;
#pragma unroll
    for (int j = 0; j < 8; ++j) {
      int k = ks * 32 + ((lane >> 4) & 3) * 8 + j;
      int n = ct * 16 + (lane & 15);
      float f = sw[k * 64 + n] * gs;
      _Float16 h = (_Float16)f;
      val[j] = hl ? (_Float16)(f - (float)h) : h;
    }
    *(v8h*)(A.outp + (size_t)b * PBH + (size_t)u * 8) = val;
  }
}

// ============ graph build: fixed-slot scatter (no hist/scan) ==================
__global__ __launch_bounds__(256) void k_bscatter2(const int* __restrict__ src,
                                                   const int* __restrict__ dst,
                                                   int* __restrict__ gcur,
                                                   unsigned* __restrict__ ebuf) {
  __shared__ int cnt[NB];
  __shared__ int base[NB];
  int t = threadIdx.x;
  for (int i = t; i < NB; i += 256) cnt[i] = 0;
  __syncthreads();
  int eb = blockIdx.x * 4096;
  unsigned pk[16];
  int bk[16], lp[16];
#pragma unroll
  for (int i = 0; i < 16; ++i) {
    int e = eb + i * 256 + t;
    if (e < NE) {
      int d = dst[e];
      int b = d >> 8;
      pk[i] = ((unsigned)src[e] << 8) | (unsigned)(d & 255);
      bk[i] = b;
      lp[i] = atomicAdd(&cnt[b], 1);
    }
  }
  __syncthreads();
  for (int i = t; i < NB; i += 256)
    base[i] = cnt[i] ? (i * SLOT + atomicAdd(&gcur[i], cnt[i])) : 0;
  __syncthreads();
#pragma unroll
  for (int i = 0; i < 16; ++i) {
    int e = eb + i * 256 + t;
    if (e < NE) {
      int p = base[bk[i]] + lp[i];
      if (p < (bk[i] + 1) * SLOT) ebuf[p] = pk[i];   // overflow guard
    }
  }
}

// per-bucket degree + scan + csr scatter; writes offs/ends (slotted csr)
__global__ __launch_bounds__(256) void k_bbuild2(const unsigned* __restrict__ ebuf,
                                                 const int* __restrict__ gcur,
                                                 int* __restrict__ offs,
                                                 int* __restrict__ ends,
                                                 float* __restrict__ invd,
                                                 int* __restrict__ csr) {
  __shared__ int dcnt[256];
  __shared__ int cur[256];
  int t = threadIdx.x;
  int b = blockIdx.x;
  int node0 = b << 8;
  int es = b * SLOT;
  int ee = es + min(gcur[b], SLOT);
  dcnt[t] = 0;
  __syncthreads();
  for (int e = es + t; e < ee; e += 256) atomicAdd(&dcnt[ebuf[e] & 255], 1);
  __syncthreads();
  int v = dcnt[t];
  cur[t] = v;
  __syncthreads();
  for (int o = 1; o < 256; o <<= 1) {
    int u = (t >= o) ? cur[t - o] : 0;
    __syncthreads();
    cur[t] += u;
    __syncthreads();
  }
  int excl = cur[t] - v;
  int node = node0 + t;
  if (node < NN) {
    offs[node] = es + excl;
    ends[node] = es + excl + v;
    invd[node] = 1.0f / fmaxf((float)v, 1.0f);
  }
  __syncthreads();
  cur[t] = es + excl;
  __syncthreads();
  for (int e = es + t; e < ee; e += 256) {
    unsigned pk = ebuf[e];
    int p = atomicAdd(&cur[pk & 255], 1);
    csr[p] = (int)(pk >> 8);
  }
}

// =================== compute-stage shared structs =============================
struct CArgs {
  const float* nf; const _Float16* wpk;
  const float* preb1; const float* preb2;
  const int* offs; const int* ends; const int* csr; const float* invd;
  _Float16 *x;
  unsigned char *f8a;
  float* sv;
  int* done;
  const float *pw1, *pb1, *pw2, *pb2, *pw3, *pb3, *pw4, *pb4;
  float* outp;
  int n;
};

struct FLinArgs {
  CArgs C;
  const _Float16* a[6];
  int pb[6];
  const unsigned char* gtab;
  const float* bias;
  _Float16* outp;
  unsigned char* out8;
  _Float16* mout;
  float* colsum;
};

// post-MLP; sv read via device-scope atomics (cross-XCD safe in last block)
__device__ __forceinline__ void post_body(int tt, const CArgs& A, float* Lf) {
  float* sh = Lf; float* h1 = Lf + 256; float* h2 = Lf + 320; float* h3 = Lf + 384;
  if (tt < 256) sh[tt] = atomicAdd(&A.sv[tt], 0.0f);
  __syncthreads();
  if (tt < 64) {
    float a = A.pb1[tt];
    for (int k = 0; k < 256; ++k) a += sh[k] * A.pw1[k * 64 + tt];
    h1[tt] = (a >= 0.f) ? a : 0.1f * a;
  }
  __syncthreads();
  if (tt < 64) {
    float a = A.pb2[tt];
    for (int k = 0; k < 64; ++k) a += h1[k] * A.pw2[k * 64 + tt];
    h2[tt] = fmaxf(a, 0.f);
  }
  __syncthreads();
  if (tt < 256) {
    float a = A.pb3[tt];
    for (int k = 0; k < 64; ++k) a += h2[k] * A.pw3[k * 256 + tt];
    h3[tt] = fmaxf(a, 0.f);
  }
  __syncthreads();
  if (tt < 64) {
    float a = A.pb4[tt];
    for (int k = 0; k < 256; ++k) a += h3[k] * A.pw4[k * 64 + tt];
    A.outp[tt] = a;
  }
}

// ====== fused gather+linear, 256 thr; global_load_lds staged gather ==========
// Gather: block's edge rows staged to LDS via wave-wide global_load_lds
// (no VGPR return -> deep MLP), then accumulated from LDS. Chunked at CH edges.
template <int NSRC, int FUSED, int DOPOST>
__global__ __launch_bounds__(256) void k_lin(FLinArgs F) {
  __shared__ unsigned char rows[CH * 64];   // 48KB staged fp8 rows
  __shared__ int sidx[CH];                  // 3KB  block-local csr
  __shared__ _Float16 atile[64 * 72];       // 9.2KB; epilogue scratch later
  __shared__ int lastflag;
  const CArgs& C = F.C;
  const int t    = threadIdx.x;
  const int lane = t & 63;
  const int wv   = t >> 6;
  const int qd   = lane >> 4;
  const int ln   = lane & 15;
  const int n0   = blockIdx.x * 64;

  // ---------------- Phase A: staged gather (4 thr/node: nd = t>>2, q = t&3) ---
  {
    const int nd = t >> 2, q = t & 3;
    const int node = n0 + nd;
    const int lastn = min(n0 + 63, C.n - 1);
    const int base = C.offs[n0];
    const int ecnt = C.ends[lastn] - base;
    float a[16];
#pragma unroll
    for (int i = 0; i < 16; ++i) a[i] = 0.f;
    int ms = 0, me = 0;
    float dinv = 0.f;
    if (node < C.n) {
      ms = C.offs[node] - base;
      me = C.ends[node] - base;
      dinv = C.invd[node];
    }
    for (int c0 = 0; c0 < ecnt; c0 += CH) {
      int cn = min(CH, ecnt - c0);
      for (int i = t; i < cn; i += 256) sidx[i] = C.csr[base + c0 + i];
      __syncthreads();
      // issue: one wave instr stages 16 rows (64 lanes x 16B), k uniform/wave
      int nch = (cn + 15) >> 4;
      for (int k = wv; k < nch; k += 4) {
        int r = k * 16 + (lane >> 2);
        int idx = sidx[r < cn ? r : cn - 1];
        const unsigned char* g = F.gtab + (size_t)idx * 64 + (size_t)(lane & 3) * 16;
        __builtin_amdgcn_global_load_lds(
            (const __attribute__((address_space(1))) unsigned int*)g,
            (__attribute__((address_space(3))) unsigned int*)(rows + k * 1024),
            16, 0, 0);
      }
      __syncthreads();   // drains vmcnt; rows ready
      int ps = ms - c0; if (ps < 0) ps = 0;
      int pe = me - c0; if (pe > cn) pe = cn;
      for (int p = ps; p < pe; ++p) {
        uint4 u = *(const uint4*)(rows + p * 64 + q * 16);
        float f[16];
        dec8x16(u, f);
#pragma unroll
        for (int i = 0; i < 16; ++i) a[i] += f[i];
      }
      __syncthreads();   // before next chunk overwrites rows
    }
    v8h o0, o1;
#pragma unroll
    for (int i = 0; i < 8; ++i) {
      o0[i] = (_Float16)(a[i] * dinv);
      o1[i] = (_Float16)(a[8 + i] * dinv);
    }
    *(v8h*)(&atile[nd * 72 + q * 16]) = o0;
    *(v8h*)(&atile[nd * 72 + q * 16 + 8]) = o1;
    if (F.mout && node < C.n) {
      *(v8h*)(F.mout + (size_t)node * 64 + q * 16) = o0;
      *(v8h*)(F.mout + (size_t)node * 64 + q * 16 + 8) = o1;
    }
  }
  __syncthreads();

  // ---------------- Phase B: MFMA serial over sources (R10 measured body) -----
  v4f acc[4];
#pragma unroll
  for (int ct = 0; ct < 4; ++ct) acc[ct] = (v4f){0.f, 0.f, 0.f, 0.f};

  const int arow = n0 + wv * 16 + ln;
  const bool arv = arow < C.n;

#pragma unroll
  for (int s = 0; s < NSRC; ++s) {
    v8h ah0, ah1;
    if (s == FUSED) {
      const _Float16* ph = atile + (wv * 16 + ln) * 72;
      ah0 = *(const v8h*)(ph + qd * 8);
      ah1 = *(const v8h*)(ph + 32 + qd * 8);
    } else if (arv) {
      const _Float16* ph = F.a[s] + (size_t)arow * 64;
      ah0 = *(const v8h*)(ph + qd * 8);
      ah1 = *(const v8h*)(ph + 32 + qd * 8);
    } else {
      v8h z;
#pragma unroll
      for (int j = 0; j < 8; ++j) z[j] = (_Float16)0.f;
      ah0 = ah1 = z;
    }
    const _Float16* pw = C.wpk + (size_t)F.pb[s] * PBH;
#pragma unroll
    for (int ct = 0; ct < 4; ++ct) {
      const _Float16* pf0 = pw + (size_t)(ct * 64 + lane) * 8;
      const _Float16* pf1 = pw + (size_t)(512 + ct * 64 + lane) * 8;
      v8h bh0 = *(const v8h*)(pf0);
      v8h bl0v = *(const v8h*)(pf0 + 2048);
      v8h bh1 = *(const v8h*)(pf1);
      v8h bl1v = *(const v8h*)(pf1 + 2048);
      acc[ct] = __builtin_amdgcn_mfma_f32_16x16x32_f16(ah0, bh0, acc[ct], 0, 0, 0);
      acc[ct] = __builtin_amdgcn_mfma_f32_16x16x32_f16(ah0, bl0v, acc[ct], 0, 0, 0);
      acc[ct] = __builtin_amdgcn_mfma_f32_16x16x32_f16(ah1, bh1, acc[ct], 0, 0, 0);
      acc[ct] = __builtin_amdgcn_mfma_f32_16x16x32_f16(ah1, bl1v, acc[ct], 0, 0, 0);
    }
  }

  float bvals[4];
#pragma unroll
  for (int ct = 0; ct < 4; ++ct) bvals[ct] = F.bias[ct * 16 + ln];

  __syncthreads();   // all atile fragment reads complete; reuse as scratch
  unsigned char* f8t = (unsigned char*)atile;   // 4KB
  float* red = (float*)&atile[2304];             // at byte 4608

  float cs[4] = {0.f, 0.f, 0.f, 0.f};
#pragma unroll
  for (int ct = 0; ct < 4; ++ct) {
#pragma unroll
    for (int r = 0; r < 4; ++r) {
      int nb = wv * 16 + qd * 4 + r;   // C/D: row=(lane>>4)*4+reg, col=lane&15
      int node = n0 + nb;
      float v = fmaxf(acc[ct][r] + bvals[ct], 0.f);   // relu (all lin stages)
      if (node < C.n) {
        if (F.outp) F.outp[(size_t)node * 64 + ct * 16 + ln] = (_Float16)v;
        if (F.out8) f8t[nb * 64 + ct * 16 + ln] = enc8(v);
        cs[ct] += v;
      }
    }
  }
#pragma unroll
  for (int ct = 0; ct < 4; ++ct) {
    float v = cs[ct];
    v += __shfl_xor(v, 16, 64);
    v += __shfl_xor(v, 32, 64);
    if (qd == 0) red[wv * 64 + ct * 16 + ln] = v;
  }
  __syncthreads();
  if (F.out8) {
    int row = t >> 2, ch = t & 3;
    if (n0 + row < C.n) {
      uint4 val = *(const uint4*)(f8t + row * 64 + ch * 16);
      *(uint4*)(F.out8 + (size_t)(n0 + row) * 64 + ch * 16) = val;
    }
  }
  if (t < 64) {
    float ssum = red[t] + red[64 + t] + red[128 + t] + red[192 + t];
    atomicAdd(&F.colsum[t], ssum);
  }

  if (DOPOST) {
    __syncthreads();
    __threadfence();
    if (t == 0)
      lastflag = (atomicAdd(C.done, 1) == (int)gridDim.x - 1);
    __syncthreads();
    if (lastflag) post_body(t, C, (float*)atile);
  }
}

// ============== fused pre-MLP (verified R10 body); 256 thr ====================
__global__ __launch_bounds__(256) void k_preF(CArgs A) {
  __shared__ _Float16 atile[64 * 72];
  const int t    = threadIdx.x;
  const int lane = t & 63;
  const int wv   = t >> 6;
  const int qd   = lane >> 4;
  const int ln   = lane & 15;
  const int n0   = blockIdx.x * 64;
  const int arow = n0 + wv * 16 + ln;
  const bool arv = arow < A.n;

  v4f acc[4];
#pragma unroll
  for (int ct = 0; ct < 4; ++ct) acc[ct] = (v4f){0.f, 0.f, 0.f, 0.f};
  v8h ah[2];

  auto domfma = [&](int pbi) {
    const _Float16* pw = A.wpk + (size_t)pbi * PBH;
#pragma unroll
    for (int ks = 0; ks < 2; ++ks) {
#pragma unroll
      for (int ct = 0; ct < 4; ++ct) {
        const _Float16* pf = pw + (size_t)(ks * 512 + ct * 64 + lane) * 8;
        v8h bh = *(const v8h*)(pf);
        v8h bl = *(const v8h*)(pf + 2048);
        acc[ct] = __builtin_amdgcn_mfma_f32_16x16x32_f16(ah[ks], bh, acc[ct], 0, 0, 0);
        acc[ct] = __builtin_amdgcn_mfma_f32_16x16x32_f16(ah[ks], bl, acc[ct], 0, 0, 0);
      }
    }
  };

  // stage 1: t0 = relu(nf@W1 + b1); K=128 as two 64-col sources (pb 0,1)
  for (int s = 0; s < 2; ++s) {
#pragma unroll
    for (int ks = 0; ks < 2; ++ks) {
      v8h hv;
      if (arv) {
        const float* p = A.nf + (size_t)arow * 128 + s * 64 + ks * 32 + qd * 8;
        float4 u0 = *(const float4*)(p);
        float4 u1 = *(const float4*)(p + 4);
        hv[0] = (_Float16)u0.x; hv[1] = (_Float16)u0.y;
        hv[2] = (_Float16)u0.z; hv[3] = (_Float16)u0.w;
        hv[4] = (_Float16)u1.x; hv[5] = (_Float16)u1.y;
        hv[6] = (_Float16)u1.z; hv[7] = (_Float16)u1.w;
      } else {
#pragma unroll
        for (int j = 0; j < 8; ++j) hv[j] = (_Float16)0.f;
      }
      ah[ks] = hv;
    }
    domfma(s);
  }

  float b1v[4];
#pragma unroll
  for (int ct = 0; ct < 4; ++ct) b1v[ct] = A.preb1[ct * 16 + ln];
#pragma unroll
  for (int ct = 0; ct < 4; ++ct) {
#pragma unroll
    for (int r = 0; r < 4; ++r) {
      int nb = wv * 16 + qd * 4 + r;
      float v = fmaxf(acc[ct][r] + b1v[ct], 0.f);
      atile[nb * 72 + ct * 16 + ln] = (_Float16)v;
    }
  }
#pragma unroll
  for (int ct = 0; ct < 4; ++ct) acc[ct] = (v4f){0.f, 0.f, 0.f, 0.f};
  __syncthreads();

  // stage 2: x = t0 @ W2 + b2 (pb 2)
  {
    const _Float16* ph = atile + (wv * 16 + ln) * 72;
    ah[0] = *(const v8h*)(ph + qd * 8);
    ah[1] = *(const v8h*)(ph + 32 + qd * 8);
  }
  domfma(2);

  float b2v[4];
#pragma unroll
  for (int ct = 0; ct < 4; ++ct) b2v[ct] = A.preb2[ct * 16 + ln];

  __syncthreads();   // all atile fragment reads complete; reuse as scratch
  unsigned char* f8t = (unsigned char*)atile;
  float* red = (float*)&atile[2304];
  float cs[4] = {0.f, 0.f, 0.f, 0.f};
#pragma unroll
  for (int ct = 0; ct < 4; ++ct) {
#pragma unroll
    for (int r = 0; r < 4; ++r) {
      int nb = wv * 16 + qd * 4 + r;
      int node = n0 + nb;
      float v = acc[ct][r] + b2v[ct];
      if (node < A.n) {
        A.x[(size_t)node * 64 + ct * 16 + ln] = (_Float16)v;
        f8t[nb * 64 + ct * 16 + ln] = enc8(v);
        cs[ct] += v;
      }
    }
  }
#pragma unroll
  for (int ct = 0; ct < 4; ++ct) {
    float v = cs[ct];
    v += __shfl_xor(v, 16, 64);
    v += __shfl_xor(v, 32, 64);
    if (qd == 0) red[wv * 64 + ct * 16 + ln] = v;
  }
  __syncthreads();
  {
    int row = t >> 2, ch = t & 3;
    if (n0 + row < A.n) {
      uint4 val = *(const uint4*)(f8t + row * 64 + ch * 16);
      *(uint4*)(A.f8a + (size_t)(n0 + row) * 64 + ch * 16) = val;
    }
  }
  if (t < 64) {
    float ssum = red[t] + red[64 + t] + red[128 + t] + red[192 + t];
    atomicAdd(&A.sv[t], ssum);
  }
}

// ================================ launcher ====================================
extern "C" void kernel_launch(void* const* d_in, const int* in_sizes, int n_in,
                              void* d_out, int out_size, void* d_ws, size_t ws_size,
                              hipStream_t stream) {
  const float* nf     = (const float*)d_in[0];
  const int*   ei     = (const int*)d_in[1];
  const float* pre_w1 = (const float*)d_in[2];
  const float* pre_b1 = (const float*)d_in[3];
  const float* pre_w2 = (const float*)d_in[4];
  const float* pre_b2 = (const float*)d_in[5];
  const float* skip   = (const float*)d_in[6];
  const float* wl0 = (const float*)d_in[7],  *bl0 = (const float*)d_in[8],  *wr0 = (const float*)d_in[9];
  const float* wl1 = (const float*)d_in[10], *bl1 = (const float*)d_in[11], *wr1 = (const float*)d_in[12];
  const float* wl2 = (const float*)d_in[13], *bl2 = (const float*)d_in[14], *wr2 = (const float*)d_in[15];
  const float* pw1 = (const float*)d_in[16], *pb1 = (const float*)d_in[17];
  const float* pw2 = (const float*)d_in[18], *pb2 = (const float*)d_in[19];
  const float* pw3 = (const float*)d_in[20], *pb3 = (const float*)d_in[21];
  const float* pw4 = (const float*)d_in[22], *pb4 = (const float*)d_in[23];
  float* out = (float*)d_out;

  const int N = NN, E = NE;

  char* ws = (char*)d_ws;
  size_t pos = 0;
  auto alloc = [&](size_t bytes) {
    char* p = ws + pos;
    pos += (bytes + 255) & ~(size_t)255;
    return (void*)p;
  };
  int*      gcur  = (int*)alloc((size_t)NB * 4);
  unsigned* ebuf  = (unsigned*)alloc((size_t)NB * SLOT * 4);
  int*      offs  = (int*)alloc((size_t)N * 4);
  int*      ends  = (int*)alloc((size_t)N * 4);
  float*    invd  = (float*)alloc((size_t)N * 4);
  int*      csr   = (int*)alloc((size_t)NB * SLOT * 4);
  const size_t PB = (size_t)N * 64 * 2;
  _Float16* x  = (_Float16*)alloc(PB);
  _Float16* h0 = (_Float16*)alloc(PB);
  _Float16* h1 = (_Float16*)alloc(PB);
  _Float16* m0 = (_Float16*)alloc(PB);
  _Float16* m1 = (_Float16*)alloc(PB);
  unsigned char* f8a = (unsigned char*)alloc((size_t)N * 64);
  unsigned char* f8b = (unsigned char*)alloc((size_t)N * 64);
  _Float16* wpk = (_Float16*)alloc((size_t)15 * PBH * 2);
  float* sv = (float*)alloc(256 * 4);
  int* done = (int*)alloc(256);

  const int* e_src = ei;
  const int* e_dst = ei + E;
  const float* wsrc[15] = {pre_w1, pre_w1 + 64 * 64, pre_w2,
                           wl0, wr0,
                           wl1, wl1 + 64 * 64, wr1, wr1 + 64 * 64,
                           wl2, wl2 + 64 * 64, wl2 + 128 * 64,
                           wr2, wr2 + 64 * 64, wr2 + 128 * 64};
  const int gi[15] = {-1, -1, -1, 0, 0, 3, 4, 3, 4, 6, 7, 8, 6, 7, 8};

  // 1) weight pre-pack + zero-init (block 15)
  {
    WPackArgs W;
    for (int i = 0; i < 15; ++i) { W.w[i] = wsrc[i]; W.gidx[i] = gi[i]; }
    W.skip = skip; W.outp = wpk;
    W.gcur = gcur; W.sv = sv; W.done = done;
    k_wpack<<<16, 256, 0, stream>>>(W);
  }

  // 2) fixed-slot edge scatter, 3) per-bucket csr build
  const int EGRID = (E + 4095) / 4096;   // 196
  k_bscatter2<<<EGRID, 256, 0, stream>>>(e_src, e_dst, gcur, ebuf);
  k_bbuild2<<<NB, 256, 0, stream>>>(ebuf, gcur, offs, ends, invd, csr);

  CArgs C;
  C.nf = nf; C.wpk = wpk; C.preb1 = pre_b1; C.preb2 = pre_b2;
  C.offs = offs; C.ends = ends; C.csr = csr; C.invd = invd;
  C.x = x; C.f8a = f8a; C.sv = sv; C.done = done;
  C.pw1 = pw1; C.pb1 = pb1; C.pw2 = pw2; C.pb2 = pb2;
  C.pw3 = pw3; C.pb3 = pb3; C.pw4 = pw4; C.pb4 = pb4;
  C.outp = out; C.n = N;

  const int LGRID = (N + 63) / 64;   // 782

  // 4) fused pre-MLP: x (fp16) + f8a + colsum sv[0:64]
  k_preF<<<LGRID, 256, 0, stream>>>(C);

  // 5) layer 0: gather f8a -> m0; h0 = relu(m0@wl0 + x@wr0 + bl0); writes f8b
  {
    FLinArgs F; F.C = C;
    F.a[0] = nullptr; F.a[1] = x; F.a[2] = nullptr; F.a[3] = nullptr;
    F.a[4] = nullptr; F.a[5] = nullptr;
    F.pb[0] = 3; F.pb[1] = 4; F.pb[2] = 0; F.pb[3] = 0; F.pb[4] = 0; F.pb[5] = 0;
    F.gtab = f8a; F.bias = bl0;
    F.outp = h0; F.out8 = f8b; F.mout = m0; F.colsum = sv + 64;
    k_lin<2, 0, 0><<<LGRID, 256, 0, stream>>>(F);
  }

  // 6) layer 1: gather f8b -> m1; sources m0,(m1),x,h0; writes f8a
  {
    FLinArgs F; F.C = C;
    F.a[0] = m0; F.a[1] = nullptr; F.a[2] = x; F.a[3] = h0;
    F.a[4] = nullptr; F.a[5] = nullptr;
    F.pb[0] = 5; F.pb[1] = 6; F.pb[2] = 7; F.pb[3] = 8; F.pb[4] = 0; F.pb[5] = 0;
    F.gtab = f8b; F.bias = bl1;
    F.outp = h1; F.out8 = f8a; F.mout = m1; F.colsum = sv + 128;
    k_lin<4, 1, 0><<<LGRID, 256, 0, stream>>>(F);
  }

  // 7) layer 2: gather f8a -> (m2); colsum only; last block runs post-MLP
  {
    FLinArgs F; F.C = C;
    F.a[0] = m0; F.a[1] = m1; F.a[2] = nullptr; F.a[3] = x;
    F.a[4] = h0; F.a[5] = h1;
    F.pb[0] = 9; F.pb[1] = 10; F.pb[2] = 11; F.pb[3] = 12; F.pb[4] = 13; F.pb[5] = 14;
    F.gtab = f8a; F.bias = bl2;
    F.outp = nullptr; F.out8 = nullptr; F.mout = nullptr; F.colsum = sv + 192;
    k_lin<6, 2, 1><<<LGRID, 256, 0, stream>>>(F);
  }
}